// Round 1
// baseline (613.962 us; speedup 1.0000x reference)
//
#include <hip/hip_runtime.h>
#include <stdint.h>

typedef unsigned short u16;
typedef __bf16 bf16x8 __attribute__((ext_vector_type(8)));
typedef float f32x4 __attribute__((ext_vector_type(4)));
typedef u16 u16x8 __attribute__((ext_vector_type(8)));

#define MFMA16(a, b, c) __builtin_amdgcn_mfma_f32_16x16x32_bf16((a), (b), (c), 0, 0, 0)

__device__ __forceinline__ u16 f2bf(float f) {
  union { float f; uint32_t u; } v; v.f = f;
  uint32_t u = v.u;
  return (u16)((u + 0x7FFFu + ((u >> 16) & 1u)) >> 16);
}

// ---------------------------------------------------------------------------
// Elementwise fp32 -> bf16 (x), vectorized
// ---------------------------------------------------------------------------
__global__ void cvt_bf16(const float* __restrict__ in, u16* __restrict__ out, int n4) {
  int i = blockIdx.x * 256 + threadIdx.x;
  if (i < n4) {
    float4 v = ((const float4*)in)[i];
    ushort4 o;
    o.x = f2bf(v.x); o.y = f2bf(v.y); o.z = f2bf(v.z); o.w = f2bf(v.w);
    ((ushort4*)out)[i] = o;
  }
}

// ---------------------------------------------------------------------------
// Transpose + convert fp32 (R x C) -> bf16 (C x R), with scale
// ---------------------------------------------------------------------------
__global__ __launch_bounds__(256) void transpose_cvt(const float* __restrict__ in,
                                                     u16* __restrict__ out,
                                                     int R, int C, float scale) {
  __shared__ float t32[32][33];
  int c0 = blockIdx.x * 32, r0 = blockIdx.y * 32;
  int tx = threadIdx.x & 31, ty = threadIdx.x >> 5;  // 32 x 8
  #pragma unroll
  for (int i = 0; i < 32; i += 8)
    t32[ty + i][tx] = in[(size_t)(r0 + ty + i) * C + c0 + tx] * scale;
  __syncthreads();
  #pragma unroll
  for (int i = 0; i < 32; i += 8)
    out[(size_t)(c0 + ty + i) * R + r0 + tx] = f2bf(t32[tx][ty + i]);
}

// ---------------------------------------------------------------------------
// Transpose V (b,t,h,d) -> Vt (b,h,d,t), bf16
// ---------------------------------------------------------------------------
__global__ __launch_bounds__(256) void transpose_v(const u16* __restrict__ V,
                                                   u16* __restrict__ Vt) {
  __shared__ u16 t32[32][33];
  int bh = blockIdx.z;
  int b = bh >> 3, h = bh & 7;
  int d0 = blockIdx.x * 32, t0 = blockIdx.y * 32;
  int tx = threadIdx.x & 31, ty = threadIdx.x >> 5;
  #pragma unroll
  for (int i = 0; i < 32; i += 8)
    t32[ty + i][tx] = V[(size_t)(b * 1024 + t0 + ty + i) * 2048 + h * 256 + d0 + tx];
  __syncthreads();
  #pragma unroll
  for (int i = 0; i < 32; i += 8)
    Vt[(size_t)bh * 262144 + (size_t)(d0 + ty + i) * 1024 + t0 + tx] = t32[tx][ty + i];
}

// ---------------------------------------------------------------------------
// C(M x N) = A(M x K) @ Bt(N x K)^T   — bf16 in, bf16 (FOUT=0) or f32 (FOUT=1) out
// 128x128 tile, BK=32, 4 waves (2x2), 16x16x32 MFMA, 4x4 frags per wave
// ---------------------------------------------------------------------------
template<int FOUT>
__global__ __launch_bounds__(256, 2) void gemm_bt(const u16* __restrict__ A,
                                                  const u16* __restrict__ Bt,
                                                  void* __restrict__ Cout,
                                                  int M, int N, int K,
                                                  int lda, int ldb, int ldc) {
  __shared__ __attribute__((aligned(16))) u16 As[128 * 32];
  __shared__ __attribute__((aligned(16))) u16 Bs[128 * 32];
  const int tid = threadIdx.x;
  const int lane = tid & 63;
  const int w = tid >> 6;
  const int wr = w >> 1, wc = w & 1;
  const int row0 = blockIdx.y * 128, col0 = blockIdx.x * 128;
  const int rr = lane & 15, kg = lane >> 4;

  f32x4 acc[4][4];
  const f32x4 fz = {0.f, 0.f, 0.f, 0.f};
  #pragma unroll
  for (int m = 0; m < 4; ++m)
    #pragma unroll
    for (int n = 0; n < 4; ++n) acc[m][n] = fz;

  for (int k0 = 0; k0 < K; k0 += 32) {
    #pragma unroll
    for (int c = 0; c < 2; ++c) {
      int idx = c * 256 + tid;          // 0..511 chunks of 16B
      int r = idx >> 2, cc = idx & 3;   // row 0..127, 8-elem chunk 0..3
      *(u16x8*)&As[r * 32 + cc * 8] = *(const u16x8*)&A[(size_t)(row0 + r) * lda + k0 + cc * 8];
      *(u16x8*)&Bs[r * 32 + cc * 8] = *(const u16x8*)&Bt[(size_t)(col0 + r) * ldb + k0 + cc * 8];
    }
    __syncthreads();
    bf16x8 af[4], bfr[4];
    #pragma unroll
    for (int m = 0; m < 4; ++m)
      af[m] = *(const bf16x8*)&As[(wr * 64 + m * 16 + rr) * 32 + kg * 8];
    #pragma unroll
    for (int n = 0; n < 4; ++n)
      bfr[n] = *(const bf16x8*)&Bs[(wc * 64 + n * 16 + rr) * 32 + kg * 8];
    #pragma unroll
    for (int m = 0; m < 4; ++m)
      #pragma unroll
      for (int n = 0; n < 4; ++n)
        acc[m][n] = MFMA16(af[m], bfr[n], acc[m][n]);
    __syncthreads();
  }

  #pragma unroll
  for (int m = 0; m < 4; ++m)
    #pragma unroll
    for (int n = 0; n < 4; ++n) {
      int r = row0 + wr * 64 + m * 16 + kg * 4;
      int c = col0 + wc * 64 + n * 16 + rr;
      #pragma unroll
      for (int j = 0; j < 4; ++j) {
        if (FOUT == 0)
          ((u16*)Cout)[(size_t)(r + j) * ldc + c] = f2bf(acc[m][n][j]);
        else
          ((float*)Cout)[(size_t)(r + j) * ldc + c] = acc[m][n][j];
      }
    }
}

// ---------------------------------------------------------------------------
// Flash attention: one (b,h) x 64 q-rows per block. 4 waves x 16 rows.
// Q,K pre-scaled by d^-1/4 (folded into weights). Q (b,t,h,d) row-stride 2048.
// Vt is (b,h,d,t). Online softmax; rows are wave-exclusive.
// ---------------------------------------------------------------------------
__global__ __launch_bounds__(256, 2) void attn_kernel(const u16* __restrict__ Q,
                                                      const u16* __restrict__ Kg,
                                                      const u16* __restrict__ Vt,
                                                      u16* __restrict__ O) {
  __shared__ __attribute__((aligned(16))) u16 Ks[64 * 256];   // 32 KB
  __shared__ __attribute__((aligned(16))) u16 Ps[4][16 * 64]; // 16 KB, per-wave
  const int tid = threadIdx.x;
  const int lane = tid & 63;
  const int w = tid >> 6;
  const int rr = lane & 15, kg = lane >> 4;
  const int bh = blockIdx.y;
  const int b = bh >> 3, h = bh & 7;
  const int q0 = blockIdx.x * 64;
  const u16* Qb = Q + (size_t)b * 1024 * 2048 + (size_t)h * 256;
  const u16* Kb = Kg + (size_t)b * 1024 * 2048 + (size_t)h * 256;
  const u16* Vb = Vt + (size_t)bh * 262144;  // [256][1024]
  u16* Ob = O + (size_t)b * 1024 * 2048 + (size_t)h * 256;

  // Q fragments in registers: wave's 16 rows x 256 k  (A-frag: row=lane&15, k=kg*8+j)
  bf16x8 qf[8];
  {
    const u16* qrow = Qb + (size_t)(q0 + w * 16 + rr) * 2048;
    #pragma unroll
    for (int ks = 0; ks < 8; ++ks) qf[ks] = *(const bf16x8*)&qrow[ks * 32 + kg * 8];
  }

  const f32x4 fz = {0.f, 0.f, 0.f, 0.f};
  f32x4 oacc[16];
  #pragma unroll
  for (int n = 0; n < 16; ++n) oacc[n] = fz;
  float mrow[4] = {-1e30f, -1e30f, -1e30f, -1e30f};
  float lrow[4] = {0.f, 0.f, 0.f, 0.f};

  for (int s0 = 0; s0 < 1024; s0 += 64) {
    // stage K tile [64 s][256 d]
    #pragma unroll
    for (int c = 0; c < 8; ++c) {
      int idx = c * 256 + tid;            // 0..2047 chunks of 16B
      int r = idx >> 5, cc = idx & 31;
      *(u16x8*)&Ks[r * 256 + cc * 8] = *(const u16x8*)&Kb[(size_t)(s0 + r) * 2048 + cc * 8];
    }
    __syncthreads();

    // S (16 rows x 64 s) = Q Kt : k-loop over d
    f32x4 sacc[4];
    #pragma unroll
    for (int n = 0; n < 4; ++n) sacc[n] = fz;
    #pragma unroll
    for (int ks = 0; ks < 8; ++ks) {
      #pragma unroll
      for (int n = 0; n < 4; ++n) {
        bf16x8 kf = *(const bf16x8*)&Ks[(n * 16 + rr) * 256 + ks * 32 + kg * 8];
        sacc[n] = MFMA16(qf[ks], kf, sacc[n]);
      }
    }

    // online softmax: lane's rows are kg*4+j; reduce across the 16 lanes of the group
    float resc[4];
    #pragma unroll
    for (int j = 0; j < 4; ++j) {
      float v = fmaxf(fmaxf(sacc[0][j], sacc[1][j]), fmaxf(sacc[2][j], sacc[3][j]));
      #pragma unroll
      for (int d = 1; d < 16; d <<= 1) v = fmaxf(v, __shfl_xor(v, d, 64));
      float mn = fmaxf(mrow[j], v);
      resc[j] = __expf(mrow[j] - mn);
      mrow[j] = mn;
    }
    float psum[4] = {0.f, 0.f, 0.f, 0.f};
    #pragma unroll
    for (int n = 0; n < 4; ++n)
      #pragma unroll
      for (int j = 0; j < 4; ++j) {
        float p = __expf(sacc[n][j] - mrow[j]);
        sacc[n][j] = p;
        psum[j] += p;
      }
    #pragma unroll
    for (int j = 0; j < 4; ++j) {
      float s = psum[j];
      #pragma unroll
      for (int d = 1; d < 16; d <<= 1) s += __shfl_xor(s, d, 64);
      lrow[j] = lrow[j] * resc[j] + s;
    }

    // write P (bf16) to wave-private swizzled LDS: byte ^= (row&7)<<4
    char* Pw = (char*)&Ps[w][0];  // [16][64] bf16, row stride 128 B
    #pragma unroll
    for (int n = 0; n < 4; ++n)
      #pragma unroll
      for (int j = 0; j < 4; ++j) {
        int prow = kg * 4 + j;
        int pbyte = prow * 128 + (((n * 16 + rr) * 2) ^ ((prow & 7) << 4));
        *(u16*)(Pw + pbyte) = f2bf(sacc[n][j]);
      }

    // rescale O
    #pragma unroll
    for (int n = 0; n < 16; ++n)
      #pragma unroll
      for (int j = 0; j < 4; ++j) oacc[n][j] *= resc[j];

    // PV: A = P (row=rr, k=s), B = V[s][d] from Vt[d][s] (contiguous s)
    #pragma unroll
    for (int ks2 = 0; ks2 < 2; ++ks2) {
      bf16x8 pf = *(const bf16x8*)(Pw + rr * 128 + ((ks2 * 64 + kg * 16) ^ ((rr & 7) << 4)));
      #pragma unroll
      for (int n = 0; n < 16; ++n) {
        bf16x8 vf = *(const bf16x8*)&Vb[(size_t)(n * 16 + rr) * 1024 + s0 + ks2 * 32 + kg * 8];
        oacc[n] = MFMA16(pf, vf, oacc[n]);
      }
    }
    __syncthreads();
  }

  // normalize + store O (b,t,h*256+d)
  #pragma unroll
  for (int j = 0; j < 4; ++j) {
    float inv = 1.0f / lrow[j];
    int r = q0 + w * 16 + kg * 4 + j;
    #pragma unroll
    for (int n = 0; n < 16; ++n)
      Ob[(size_t)r * 2048 + n * 16 + rr] = f2bf(oacc[n][j] * inv);
  }
}

// ---------------------------------------------------------------------------
extern "C" void kernel_launch(void* const* d_in, const int* in_sizes, int n_in,
                              void* d_out, int out_size, void* d_ws, size_t ws_size,
                              hipStream_t stream) {
  const float* x  = (const float*)d_in[0];
  const float* Wq = (const float*)d_in[1];
  const float* Wk = (const float*)d_in[2];
  const float* Wv = (const float*)d_in[3];
  const float* Wu = (const float*)d_in[4];

  // workspace layout (u16 units)
  u16* xb  = (u16*)d_ws;                 // 8192*256
  u16* WtQ = xb  + 8192 * 256;           // 2048*256
  u16* WtK = WtQ + 2048 * 256;
  u16* WtV = WtK + 2048 * 256;
  u16* Wut = WtV + 2048 * 256;           // 256*2048
  u16* Qm  = Wut + 2048 * 256;           // 8192*2048 each below
  u16* Km  = Qm  + (size_t)8192 * 2048;
  u16* Vm  = Km  + (size_t)8192 * 2048;
  u16* Vtm = Vm  + (size_t)8192 * 2048;
  u16* Om  = Vtm + (size_t)8192 * 2048;

  const float inv4 = 0.25f;  // 256^(-1/4)

  cvt_bf16<<<2048, 256, 0, stream>>>(x, xb, 8192 * 256 / 4);
  transpose_cvt<<<dim3(64, 8), 256, 0, stream>>>(Wq, WtQ, 256, 2048, inv4);
  transpose_cvt<<<dim3(64, 8), 256, 0, stream>>>(Wk, WtK, 256, 2048, inv4);
  transpose_cvt<<<dim3(64, 8), 256, 0, stream>>>(Wv, WtV, 256, 2048, 1.0f);
  transpose_cvt<<<dim3(8, 64), 256, 0, stream>>>(Wu, Wut, 2048, 256, 1.0f);

  gemm_bt<0><<<dim3(16, 64), 256, 0, stream>>>(xb, WtQ, Qm, 8192, 2048, 256, 256, 256, 2048);
  gemm_bt<0><<<dim3(16, 64), 256, 0, stream>>>(xb, WtK, Km, 8192, 2048, 256, 256, 256, 2048);
  gemm_bt<0><<<dim3(16, 64), 256, 0, stream>>>(xb, WtV, Vm, 8192, 2048, 256, 256, 256, 2048);

  transpose_v<<<dim3(8, 32, 64), 256, 0, stream>>>(Vm, Vtm);

  attn_kernel<<<dim3(16, 64), 256, 0, stream>>>(Qm, Km, Vtm, Om);

  gemm_bt<1><<<dim3(2, 64), 256, 0, stream>>>(Om, Wut, d_out, 8192, 256, 2048, 2048, 2048, 256);
}

// Round 2
// 449.526 us; speedup vs baseline: 1.3658x; 1.3658x over previous
//
#include <hip/hip_runtime.h>
#include <stdint.h>

typedef unsigned short u16;
typedef __bf16 bf16x8 __attribute__((ext_vector_type(8)));
typedef float f32x4 __attribute__((ext_vector_type(4)));
typedef u16 u16x8 __attribute__((ext_vector_type(8)));

#define MFMA16(a, b, c) __builtin_amdgcn_mfma_f32_16x16x32_bf16((a), (b), (c), 0, 0, 0)

__device__ __forceinline__ u16 f2bf(float f) {
  union { float f; uint32_t u; } v; v.f = f;
  uint32_t u = v.u;
  return (u16)((u + 0x7FFFu + ((u >> 16) & 1u)) >> 16);
}

// async global(16B/lane) -> LDS, wave-uniform dest base + lane*16
__device__ __forceinline__ void gload_lds16(const u16* g, u16* l) {
  __builtin_amdgcn_global_load_lds((const __attribute__((address_space(1))) void*)g,
                                   (__attribute__((address_space(3))) void*)l, 16, 0, 0);
}

// ---------------------------------------------------------------------------
// Elementwise fp32 -> bf16 (x), vectorized
// ---------------------------------------------------------------------------
__global__ void cvt_bf16(const float* __restrict__ in, u16* __restrict__ out, int n4) {
  int i = blockIdx.x * 256 + threadIdx.x;
  if (i < n4) {
    float4 v = ((const float4*)in)[i];
    ushort4 o;
    o.x = f2bf(v.x); o.y = f2bf(v.y); o.z = f2bf(v.z); o.w = f2bf(v.w);
    ((ushort4*)out)[i] = o;
  }
}

// ---------------------------------------------------------------------------
// Transpose + convert fp32 (R x C) -> bf16 (C x R), with scale
// ---------------------------------------------------------------------------
__global__ __launch_bounds__(256) void transpose_cvt(const float* __restrict__ in,
                                                     u16* __restrict__ out,
                                                     int R, int C, float scale) {
  __shared__ float t32[32][33];
  int c0 = blockIdx.x * 32, r0 = blockIdx.y * 32;
  int tx = threadIdx.x & 31, ty = threadIdx.x >> 5;  // 32 x 8
  #pragma unroll
  for (int i = 0; i < 32; i += 8)
    t32[ty + i][tx] = in[(size_t)(r0 + ty + i) * C + c0 + tx] * scale;
  __syncthreads();
  #pragma unroll
  for (int i = 0; i < 32; i += 8)
    out[(size_t)(c0 + ty + i) * R + r0 + tx] = f2bf(t32[tx][ty + i]);
}

// ---------------------------------------------------------------------------
// Transpose V (b,t,h,d) -> Vt (b,h,d,t), bf16
// ---------------------------------------------------------------------------
__global__ __launch_bounds__(256) void transpose_v(const u16* __restrict__ V,
                                                   u16* __restrict__ Vt) {
  __shared__ u16 t32[32][33];
  int bh = blockIdx.z;
  int b = bh >> 3, h = bh & 7;
  int d0 = blockIdx.x * 32, t0 = blockIdx.y * 32;
  int tx = threadIdx.x & 31, ty = threadIdx.x >> 5;
  #pragma unroll
  for (int i = 0; i < 32; i += 8)
    t32[ty + i][tx] = V[(size_t)(b * 1024 + t0 + ty + i) * 2048 + h * 256 + d0 + tx];
  __syncthreads();
  #pragma unroll
  for (int i = 0; i < 32; i += 8)
    Vt[(size_t)bh * 262144 + (size_t)(d0 + ty + i) * 1024 + t0 + tx] = t32[tx][ty + i];
}

// ---------------------------------------------------------------------------
// C(M x N) = A(M x K) @ Bt(N x K)^T   — bf16 in, bf16 (FOUT=0) or f32 (FOUT=1) out
// 128x128 tile, BK=32, 4 waves (2x2), 16x16x32 MFMA, global_load_lds staging
// ---------------------------------------------------------------------------
template<int FOUT>
__global__ __launch_bounds__(256, 2) void gemm_bt(const u16* __restrict__ A,
                                                  const u16* __restrict__ Bt,
                                                  void* __restrict__ Cout,
                                                  int M, int N, int K,
                                                  int lda, int ldb, int ldc) {
  __shared__ __attribute__((aligned(16))) u16 As[128 * 32];
  __shared__ __attribute__((aligned(16))) u16 Bs[128 * 32];
  const int tid = threadIdx.x;
  const int lane = tid & 63;
  const int w = tid >> 6;
  const int wr = w >> 1, wc = w & 1;
  const int row0 = blockIdx.y * 128, col0 = blockIdx.x * 128;
  const int rr = lane & 15, kg = lane >> 4;

  f32x4 acc[4][4];
  const f32x4 fz = {0.f, 0.f, 0.f, 0.f};
  #pragma unroll
  for (int m = 0; m < 4; ++m)
    #pragma unroll
    for (int n = 0; n < 4; ++n) acc[m][n] = fz;

  for (int k0 = 0; k0 < K; k0 += 32) {
    #pragma unroll
    for (int c = 0; c < 2; ++c) {
      int Lb = c * 256 + w * 64;        // wave's 16B-chunk base (64 chunks/wave)
      int L = Lb + lane;                // 0..511
      int r = L >> 2, cc = L & 3;       // row 0..127, chunk-in-row 0..3
      gload_lds16(&A[(size_t)(row0 + r) * lda + k0 + cc * 8], &As[Lb << 3]);
      gload_lds16(&Bt[(size_t)(col0 + r) * ldb + k0 + cc * 8], &Bs[Lb << 3]);
    }
    __syncthreads();
    bf16x8 af[4], bfr[4];
    #pragma unroll
    for (int m = 0; m < 4; ++m)
      af[m] = *(const bf16x8*)&As[(wr * 64 + m * 16 + rr) * 32 + kg * 8];
    #pragma unroll
    for (int n = 0; n < 4; ++n)
      bfr[n] = *(const bf16x8*)&Bs[(wc * 64 + n * 16 + rr) * 32 + kg * 8];
    #pragma unroll
    for (int m = 0; m < 4; ++m)
      #pragma unroll
      for (int n = 0; n < 4; ++n)
        acc[m][n] = MFMA16(af[m], bfr[n], acc[m][n]);
    __syncthreads();
  }

  #pragma unroll
  for (int m = 0; m < 4; ++m)
    #pragma unroll
    for (int n = 0; n < 4; ++n) {
      int r = row0 + wr * 64 + m * 16 + kg * 4;
      int c = col0 + wc * 64 + n * 16 + rr;
      #pragma unroll
      for (int j = 0; j < 4; ++j) {
        if (FOUT == 0)
          ((u16*)Cout)[(size_t)(r + j) * ldc + c] = f2bf(acc[m][n][j]);
        else
          ((float*)Cout)[(size_t)(r + j) * ldc + c] = acc[m][n][j];
      }
    }
}

// ---------------------------------------------------------------------------
// Flash attention. One (b,h) x 64 q-rows per block, 4 waves x 16 rows.
// K tile [64][256] staged via global_load_lds with chunk-XOR swizzle:
//   LDS[r][c16] holds global chunk (c16 ^ (r&7))  (both-sides involution)
// Next K tile prefetched async after the post-QK^T barrier (hides under PV).
// Grid: 1D 1024 with bijective XCD swizzle (each XCD -> 8 consecutive bh).
// ---------------------------------------------------------------------------
__global__ __launch_bounds__(256, 2) void attn_kernel(const u16* __restrict__ Q,
                                                      const u16* __restrict__ Kg,
                                                      const u16* __restrict__ Vt,
                                                      u16* __restrict__ O) {
  __shared__ __attribute__((aligned(16))) u16 Ks[64 * 256];   // 32 KB
  __shared__ __attribute__((aligned(16))) u16 Ps[4][16 * 64]; // 8 KB, per-wave
  const int tid = threadIdx.x;
  const int lane = tid & 63;
  const int w = tid >> 6;
  const int rr = lane & 15, kg = lane >> 4;
  const int bid = blockIdx.x;
  const int swz = (bid & 7) * 128 + (bid >> 3);  // XCD-contiguous
  const int bh = swz >> 4;
  const int b = bh >> 3, h = bh & 7;
  const int q0 = (swz & 15) * 64;
  const u16* Qb = Q + (size_t)b * 1024 * 2048 + (size_t)h * 256;
  const u16* Kb = Kg + (size_t)b * 1024 * 2048 + (size_t)h * 256;
  const u16* Vb = Vt + (size_t)bh * 262144;  // [256][1024]
  u16* Ob = O + (size_t)b * 1024 * 2048 + (size_t)h * 256;

  // stage K tile s0 via global_load_lds, inverse-swizzled global source
  auto stage_k = [&](int s0) {
    #pragma unroll
    for (int c = 0; c < 8; ++c) {
      int Lb = (c * 4 + w) * 64;          // wave's chunk base (64 chunks = 2 rows)
      int L = Lb + lane;                  // 0..2047
      int r = L >> 5, cc = L & 31;
      gload_lds16(&Kb[(size_t)(s0 + r) * 2048 + ((cc ^ (r & 7)) << 3)],
                  &Ks[Lb << 3]);
    }
  };

  stage_k(0);

  // Q fragments in registers: wave's 16 rows x 256 k  (A-frag: row=lane&15, k=kg*8+j)
  bf16x8 qf[8];
  {
    const u16* qrow = Qb + (size_t)(q0 + w * 16 + rr) * 2048;
    #pragma unroll
    for (int ks = 0; ks < 8; ++ks) qf[ks] = *(const bf16x8*)&qrow[ks * 32 + kg * 8];
  }

  const f32x4 fz = {0.f, 0.f, 0.f, 0.f};
  f32x4 oacc[16];
  #pragma unroll
  for (int n = 0; n < 16; ++n) oacc[n] = fz;
  float mrow[4] = {-1e30f, -1e30f, -1e30f, -1e30f};
  float lrow[4] = {0.f, 0.f, 0.f, 0.f};

  __syncthreads();  // drains vmcnt: K tile 0 + qf in LDS/regs

  for (int s0 = 0; s0 < 1024; s0 += 64) {
    // S (16 rows x 64 s) = Q Kt, swizzled Ks reads (conflict-free)
    f32x4 sacc[4];
    #pragma unroll
    for (int n = 0; n < 4; ++n) sacc[n] = fz;
    #pragma unroll
    for (int ks = 0; ks < 8; ++ks) {
      #pragma unroll
      for (int n = 0; n < 4; ++n) {
        int row = n * 16 + rr;
        bf16x8 kf = *(const bf16x8*)&Ks[row * 256 + (((ks * 4 + kg) ^ (row & 7)) << 3)];
        sacc[n] = MFMA16(qf[ks], kf, sacc[n]);
      }
    }
    __syncthreads();               // all waves done reading Ks
    if (s0 < 960) stage_k(s0 + 64);  // async prefetch, lands before end barrier

    // online softmax: lane's rows are kg*4+j; reduce across 16 lanes
    float resc[4];
    #pragma unroll
    for (int j = 0; j < 4; ++j) {
      float v = fmaxf(fmaxf(sacc[0][j], sacc[1][j]), fmaxf(sacc[2][j], sacc[3][j]));
      #pragma unroll
      for (int d = 1; d < 16; d <<= 1) v = fmaxf(v, __shfl_xor(v, d, 64));
      float mn = fmaxf(mrow[j], v);
      resc[j] = __expf(mrow[j] - mn);
      mrow[j] = mn;
    }
    float psum[4] = {0.f, 0.f, 0.f, 0.f};
    #pragma unroll
    for (int n = 0; n < 4; ++n)
      #pragma unroll
      for (int j = 0; j < 4; ++j) {
        float p = __expf(sacc[n][j] - mrow[j]);
        sacc[n][j] = p;
        psum[j] += p;
      }
    #pragma unroll
    for (int j = 0; j < 4; ++j) {
      float s = psum[j];
      #pragma unroll
      for (int d = 1; d < 16; d <<= 1) s += __shfl_xor(s, d, 64);
      lrow[j] = lrow[j] * resc[j] + s;
    }

    // write P (bf16) to wave-private swizzled LDS: byte ^= (row&7)<<4
    char* Pw = (char*)&Ps[w][0];  // [16][64] bf16, row stride 128 B
    #pragma unroll
    for (int n = 0; n < 4; ++n)
      #pragma unroll
      for (int j = 0; j < 4; ++j) {
        int prow = kg * 4 + j;
        int pbyte = prow * 128 + (((n * 16 + rr) * 2) ^ ((prow & 7) << 4));
        *(u16*)(Pw + pbyte) = f2bf(sacc[n][j]);
      }

    // rescale O
    #pragma unroll
    for (int n = 0; n < 16; ++n)
      #pragma unroll
      for (int j = 0; j < 4; ++j) oacc[n][j] *= resc[j];

    // PV: A = P (row=rr, k=s), B = V[s][d] from Vt[d][s] (contiguous s)
    #pragma unroll
    for (int ks2 = 0; ks2 < 2; ++ks2) {
      bf16x8 pf = *(const bf16x8*)(Pw + rr * 128 + ((ks2 * 64 + kg * 16) ^ ((rr & 7) << 4)));
      #pragma unroll
      for (int n = 0; n < 16; ++n) {
        bf16x8 vf = *(const bf16x8*)&Vb[(size_t)(n * 16 + rr) * 1024 + s0 + ks2 * 32 + kg * 8];
        oacc[n] = MFMA16(pf, vf, oacc[n]);
      }
    }
    __syncthreads();  // drains vmcnt(0): K prefetch landed; Ks safe for next QK^T
  }

  // normalize + store O (b,t,h*256+d)
  #pragma unroll
  for (int j = 0; j < 4; ++j) {
    float inv = 1.0f / lrow[j];
    int r = q0 + w * 16 + kg * 4 + j;
    #pragma unroll
    for (int n = 0; n < 16; ++n)
      Ob[(size_t)r * 2048 + n * 16 + rr] = f2bf(oacc[n][j] * inv);
  }
}

// ---------------------------------------------------------------------------
extern "C" void kernel_launch(void* const* d_in, const int* in_sizes, int n_in,
                              void* d_out, int out_size, void* d_ws, size_t ws_size,
                              hipStream_t stream) {
  const float* x  = (const float*)d_in[0];
  const float* Wq = (const float*)d_in[1];
  const float* Wk = (const float*)d_in[2];
  const float* Wv = (const float*)d_in[3];
  const float* Wu = (const float*)d_in[4];

  // workspace layout (u16 units)
  u16* xb  = (u16*)d_ws;                 // 8192*256
  u16* WtQ = xb  + 8192 * 256;           // 2048*256
  u16* WtK = WtQ + 2048 * 256;
  u16* WtV = WtK + 2048 * 256;
  u16* Wut = WtV + 2048 * 256;           // 256*2048
  u16* Qm  = Wut + 2048 * 256;           // 8192*2048 each below
  u16* Km  = Qm  + (size_t)8192 * 2048;
  u16* Vm  = Km  + (size_t)8192 * 2048;
  u16* Vtm = Vm  + (size_t)8192 * 2048;
  u16* Om  = Vtm + (size_t)8192 * 2048;

  const float inv4 = 0.25f;  // 256^(-1/4)

  cvt_bf16<<<2048, 256, 0, stream>>>(x, xb, 8192 * 256 / 4);
  transpose_cvt<<<dim3(64, 8), 256, 0, stream>>>(Wq, WtQ, 256, 2048, inv4);
  transpose_cvt<<<dim3(64, 8), 256, 0, stream>>>(Wk, WtK, 256, 2048, inv4);
  transpose_cvt<<<dim3(64, 8), 256, 0, stream>>>(Wv, WtV, 256, 2048, 1.0f);
  transpose_cvt<<<dim3(8, 64), 256, 0, stream>>>(Wu, Wut, 2048, 256, 1.0f);

  gemm_bt<0><<<dim3(16, 64), 256, 0, stream>>>(xb, WtQ, Qm, 8192, 2048, 256, 256, 256, 2048);
  gemm_bt<0><<<dim3(16, 64), 256, 0, stream>>>(xb, WtK, Km, 8192, 2048, 256, 256, 256, 2048);
  gemm_bt<0><<<dim3(16, 64), 256, 0, stream>>>(xb, WtV, Vm, 8192, 2048, 256, 256, 256, 2048);

  transpose_v<<<dim3(8, 32, 64), 256, 0, stream>>>(Vm, Vtm);

  attn_kernel<<<1024, 256, 0, stream>>>(Qm, Km, Vtm, Om);

  gemm_bt<1><<<dim3(2, 64), 256, 0, stream>>>(Om, Wut, d_out, 8192, 256, 2048, 2048, 2048, 256);
}

// Round 3
// 241.458 us; speedup vs baseline: 2.5427x; 1.8617x over previous
//
#include <hip/hip_runtime.h>
#include <stdint.h>

typedef unsigned short u16;
typedef __bf16 bf16x8 __attribute__((ext_vector_type(8)));
typedef float f32x4 __attribute__((ext_vector_type(4)));
typedef u16 u16x8 __attribute__((ext_vector_type(8)));

#define MFMA16(a, b, c) __builtin_amdgcn_mfma_f32_16x16x32_bf16((a), (b), (c), 0, 0, 0)

__device__ __forceinline__ u16 f2bf(float f) {
  union { float f; uint32_t u; } v; v.f = f;
  uint32_t u = v.u;
  return (u16)((u + 0x7FFFu + ((u >> 16) & 1u)) >> 16);
}

// async global(16B/lane) -> LDS, wave-uniform dest base + lane*16
__device__ __forceinline__ void gload_lds16(const u16* g, u16* l) {
  __builtin_amdgcn_global_load_lds((const __attribute__((address_space(1))) void*)g,
                                   (__attribute__((address_space(3))) void*)l, 16, 0, 0);
}

// ---------------------------------------------------------------------------
// Elementwise fp32 -> bf16 (x), vectorized
// ---------------------------------------------------------------------------
__global__ void cvt_bf16(const float* __restrict__ in, u16* __restrict__ out, int n4) {
  int i = blockIdx.x * 256 + threadIdx.x;
  if (i < n4) {
    float4 v = ((const float4*)in)[i];
    ushort4 o;
    o.x = f2bf(v.x); o.y = f2bf(v.y); o.z = f2bf(v.z); o.w = f2bf(v.w);
    ((ushort4*)out)[i] = o;
  }
}

// ---------------------------------------------------------------------------
// Transpose + convert fp32 (R x C) -> bf16 (C x R), with scale
// ---------------------------------------------------------------------------
__global__ __launch_bounds__(256) void transpose_cvt(const float* __restrict__ in,
                                                     u16* __restrict__ out,
                                                     int R, int C, float scale) {
  __shared__ float t32[32][33];
  int c0 = blockIdx.x * 32, r0 = blockIdx.y * 32;
  int tx = threadIdx.x & 31, ty = threadIdx.x >> 5;  // 32 x 8
  #pragma unroll
  for (int i = 0; i < 32; i += 8)
    t32[ty + i][tx] = in[(size_t)(r0 + ty + i) * C + c0 + tx] * scale;
  __syncthreads();
  #pragma unroll
  for (int i = 0; i < 32; i += 8)
    out[(size_t)(c0 + ty + i) * R + r0 + tx] = f2bf(t32[tx][ty + i]);
}

// ---------------------------------------------------------------------------
// Transpose V (b,t,h,d) -> Vt (b,h,d,t), bf16
// ---------------------------------------------------------------------------
__global__ __launch_bounds__(256) void transpose_v(const u16* __restrict__ V,
                                                   u16* __restrict__ Vt) {
  __shared__ u16 t32[32][33];
  int bh = blockIdx.z;
  int b = bh >> 3, h = bh & 7;
  int d0 = blockIdx.x * 32, t0 = blockIdx.y * 32;
  int tx = threadIdx.x & 31, ty = threadIdx.x >> 5;
  #pragma unroll
  for (int i = 0; i < 32; i += 8)
    t32[ty + i][tx] = V[(size_t)(b * 1024 + t0 + ty + i) * 2048 + h * 256 + d0 + tx];
  __syncthreads();
  #pragma unroll
  for (int i = 0; i < 32; i += 8)
    Vt[(size_t)bh * 262144 + (size_t)(d0 + ty + i) * 1024 + t0 + tx] = t32[tx][ty + i];
}

// ---------------------------------------------------------------------------
// C(M x N) = A(M x K) @ Bt(N x K)^T   — bf16 in, bf16 (FOUT=0) or f32 (FOUT=1) out
// 128x128 tile, BK=32, 4 waves (2x2), 16x16x32 MFMA, global_load_lds staging
// ---------------------------------------------------------------------------
template<int FOUT>
__global__ __launch_bounds__(256, 2) void gemm_bt(const u16* __restrict__ A,
                                                  const u16* __restrict__ Bt,
                                                  void* __restrict__ Cout,
                                                  int M, int N, int K,
                                                  int lda, int ldb, int ldc) {
  __shared__ __attribute__((aligned(16))) u16 As[128 * 32];
  __shared__ __attribute__((aligned(16))) u16 Bs[128 * 32];
  const int tid = threadIdx.x;
  const int lane = tid & 63;
  const int w = tid >> 6;
  const int wr = w >> 1, wc = w & 1;
  const int row0 = blockIdx.y * 128, col0 = blockIdx.x * 128;
  const int rr = lane & 15, kg = lane >> 4;

  f32x4 acc[4][4];
  const f32x4 fz = {0.f, 0.f, 0.f, 0.f};
  #pragma unroll
  for (int m = 0; m < 4; ++m)
    #pragma unroll
    for (int n = 0; n < 4; ++n) acc[m][n] = fz;

  for (int k0 = 0; k0 < K; k0 += 32) {
    #pragma unroll
    for (int c = 0; c < 2; ++c) {
      int Lb = c * 256 + w * 64;        // wave's 16B-chunk base (64 chunks/wave)
      int L = Lb + lane;                // 0..511
      int r = L >> 2, cc = L & 3;       // row 0..127, chunk-in-row 0..3
      gload_lds16(&A[(size_t)(row0 + r) * lda + k0 + cc * 8], &As[Lb << 3]);
      gload_lds16(&Bt[(size_t)(col0 + r) * ldb + k0 + cc * 8], &Bs[Lb << 3]);
    }
    __syncthreads();
    bf16x8 af[4], bfr[4];
    #pragma unroll
    for (int m = 0; m < 4; ++m)
      af[m] = *(const bf16x8*)&As[(wr * 64 + m * 16 + rr) * 32 + kg * 8];
    #pragma unroll
    for (int n = 0; n < 4; ++n)
      bfr[n] = *(const bf16x8*)&Bs[(wc * 64 + n * 16 + rr) * 32 + kg * 8];
    #pragma unroll
    for (int m = 0; m < 4; ++m)
      #pragma unroll
      for (int n = 0; n < 4; ++n)
        acc[m][n] = MFMA16(af[m], bfr[n], acc[m][n]);
    __syncthreads();
  }

  #pragma unroll
  for (int m = 0; m < 4; ++m)
    #pragma unroll
    for (int n = 0; n < 4; ++n) {
      int r = row0 + wr * 64 + m * 16 + kg * 4;
      int c = col0 + wc * 64 + n * 16 + rr;
      #pragma unroll
      for (int j = 0; j < 4; ++j) {
        if (FOUT == 0)
          ((u16*)Cout)[(size_t)(r + j) * ldc + c] = f2bf(acc[m][n][j]);
        else
          ((float*)Cout)[(size_t)(r + j) * ldc + c] = acc[m][n][j];
      }
    }
}

// ---------------------------------------------------------------------------
// Flash attention. One (b,h) x 128 q-rows per block, 8 waves x 16 rows.
// K [64][256] and V^T [256][64] both staged in LDS, double-buffered,
// chunk-XOR swizzled (linear LDS dest + inverse-swizzled global source).
// Stage of tile t+1 issued at TOP of iter t; single barrier per iter drains it.
// LDS: 2*32K (K) + 2*32K (V) + 16K (P) = 144 KB -> 1 block/CU, 8 waves.
// ---------------------------------------------------------------------------
__global__ __launch_bounds__(512, 2) void attn_kernel(const u16* __restrict__ Q,
                                                      const u16* __restrict__ Kg,
                                                      const u16* __restrict__ Vt,
                                                      u16* __restrict__ O) {
  __shared__ __attribute__((aligned(16))) u16 smem[73728];
  u16* Ks = smem;              // [2][64][256]
  u16* Vs = smem + 32768;      // [2][256][64]
  u16* Ps = smem + 65536;      // [8][16][64]
  const int tid = threadIdx.x;
  const int lane = tid & 63;
  const int w = tid >> 6;
  const int rr = lane & 15, kg = lane >> 4;
  const int bid = blockIdx.x;
  const int swz = (bid & 7) * 64 + (bid >> 3);  // XCD-contiguous, bijective (512 blocks)
  const int bh = swz >> 3;
  const int b = bh >> 3, h = bh & 7;
  const int q0 = (swz & 7) * 128;
  const u16* Qb = Q + (size_t)b * 1024 * 2048 + (size_t)h * 256;
  const u16* Kb = Kg + (size_t)b * 1024 * 2048 + (size_t)h * 256;
  const u16* Vb = Vt + (size_t)bh * 262144;  // [256][1024]
  u16* Ob = O + (size_t)b * 1024 * 2048 + (size_t)h * 256;

  // stage K tile [64][256] and V tile [256][64] into buffer sb, swizzled
  auto stage_kv = [&](int sb, int s0) {
    u16* Kd = Ks + sb * 16384;
    u16* Vd = Vs + sb * 16384;
    #pragma unroll
    for (int c = 0; c < 4; ++c) {
      int Lb = (c * 8 + w) * 64;          // wave-uniform chunk base
      int L = Lb + lane;                  // 0..2047 (16B chunks)
      int r = L >> 5, cc = L & 31;        // K: row 0..63, chunk 0..31
      gload_lds16(&Kb[(size_t)(s0 + r) * 2048 + ((cc ^ (r & 7)) << 3)], &Kd[Lb << 3]);
      int rv = L >> 3, cv = L & 7;        // V: d-row 0..255, chunk 0..7
      gload_lds16(&Vb[(size_t)rv * 1024 + s0 + ((cv ^ (rv & 7)) << 3)], &Vd[Lb << 3]);
    }
  };

  stage_kv(0, 0);

  // Q fragments: wave's 16 rows x 256 k  (A-frag: row=lane&15, k=kg*8+j)
  bf16x8 qf[8];
  {
    const u16* qrow = Qb + (size_t)(q0 + w * 16 + rr) * 2048;
    #pragma unroll
    for (int ks = 0; ks < 8; ++ks) qf[ks] = *(const bf16x8*)&qrow[ks * 32 + kg * 8];
  }

  const f32x4 fz = {0.f, 0.f, 0.f, 0.f};
  f32x4 oacc[16];
  #pragma unroll
  for (int n = 0; n < 16; ++n) oacc[n] = fz;
  float mrow[4] = {-1e30f, -1e30f, -1e30f, -1e30f};
  float lrow[4] = {0.f, 0.f, 0.f, 0.f};

  __syncthreads();  // drains vmcnt: K/V tile 0 staged, qf loaded

  int buf = 0;
  for (int t = 0; t < 16; ++t) {
    if (t < 15) stage_kv(buf ^ 1, (t + 1) * 64);  // async, lands by end barrier

    // S (16 rows x 64 s) = Q K^T from swizzled Ks[buf]
    const u16* Kd = Ks + buf * 16384;
    f32x4 sacc[4];
    #pragma unroll
    for (int n = 0; n < 4; ++n) sacc[n] = fz;
    __builtin_amdgcn_s_setprio(1);
    #pragma unroll
    for (int ks = 0; ks < 8; ++ks) {
      #pragma unroll
      for (int n = 0; n < 4; ++n) {
        int row = n * 16 + rr;
        bf16x8 kf = *(const bf16x8*)&Kd[row * 256 + (((ks * 4 + kg) ^ (row & 7)) << 3)];
        sacc[n] = MFMA16(qf[ks], kf, sacc[n]);
      }
    }
    __builtin_amdgcn_s_setprio(0);

    // online softmax: lane's rows are kg*4+j; reduce across 16 lanes
    float resc[4];
    #pragma unroll
    for (int j = 0; j < 4; ++j) {
      float v = fmaxf(fmaxf(sacc[0][j], sacc[1][j]), fmaxf(sacc[2][j], sacc[3][j]));
      #pragma unroll
      for (int d = 1; d < 16; d <<= 1) v = fmaxf(v, __shfl_xor(v, d, 64));
      float mn = fmaxf(mrow[j], v);
      resc[j] = __expf(mrow[j] - mn);
      mrow[j] = mn;
    }
    float psum[4] = {0.f, 0.f, 0.f, 0.f};
    #pragma unroll
    for (int n = 0; n < 4; ++n)
      #pragma unroll
      for (int j = 0; j < 4; ++j) {
        float p = __expf(sacc[n][j] - mrow[j]);
        sacc[n][j] = p;
        psum[j] += p;
      }
    #pragma unroll
    for (int j = 0; j < 4; ++j) {
      float s = psum[j];
      #pragma unroll
      for (int d = 1; d < 16; d <<= 1) s += __shfl_xor(s, d, 64);
      lrow[j] = lrow[j] * resc[j] + s;
    }

    // write P (bf16) to wave-private swizzled LDS: byte ^= (row&7)<<4
    char* Pw = (char*)&Ps[w * 1024];  // [16][64] bf16, row stride 128 B
    #pragma unroll
    for (int n = 0; n < 4; ++n)
      #pragma unroll
      for (int j = 0; j < 4; ++j) {
        int prow = kg * 4 + j;
        int pbyte = prow * 128 + (((n * 16 + rr) * 2) ^ ((prow & 7) << 4));
        *(u16*)(Pw + pbyte) = f2bf(sacc[n][j]);
      }

    // rescale O
    #pragma unroll
    for (int n = 0; n < 16; ++n)
      #pragma unroll
      for (int j = 0; j < 4; ++j) oacc[n][j] *= resc[j];

    // PV: A = P (row=rr, k=s), B = V^T rows (d), swizzled Vs[buf] reads
    const u16* Vd = Vs + buf * 16384;
    #pragma unroll
    for (int ks2 = 0; ks2 < 2; ++ks2) {
      bf16x8 pf = *(const bf16x8*)(Pw + rr * 128 + ((ks2 * 64 + kg * 16) ^ ((rr & 7) << 4)));
      __builtin_amdgcn_s_setprio(1);
      #pragma unroll
      for (int n = 0; n < 16; ++n) {
        int row = n * 16 + rr;
        bf16x8 vf = *(const bf16x8*)&Vd[row * 64 + (((ks2 * 4 + kg) ^ (row & 7)) << 3)];
        oacc[n] = MFMA16(pf, vf, oacc[n]);
      }
      __builtin_amdgcn_s_setprio(0);
    }

    __syncthreads();  // drains vmcnt(0): next K/V staged; bufs safe to swap
    buf ^= 1;
  }

  // normalize + store O (b,t,h*256+d)
  #pragma unroll
  for (int j = 0; j < 4; ++j) {
    float inv = 1.0f / lrow[j];
    int r = q0 + w * 16 + kg * 4 + j;
    #pragma unroll
    for (int n = 0; n < 16; ++n)
      Ob[(size_t)r * 2048 + n * 16 + rr] = f2bf(oacc[n][j] * inv);
  }
}

// ---------------------------------------------------------------------------
extern "C" void kernel_launch(void* const* d_in, const int* in_sizes, int n_in,
                              void* d_out, int out_size, void* d_ws, size_t ws_size,
                              hipStream_t stream) {
  const float* x  = (const float*)d_in[0];
  const float* Wq = (const float*)d_in[1];
  const float* Wk = (const float*)d_in[2];
  const float* Wv = (const float*)d_in[3];
  const float* Wu = (const float*)d_in[4];

  // workspace layout (u16 units)
  u16* xb  = (u16*)d_ws;                 // 8192*256
  u16* WtQ = xb  + 8192 * 256;           // 2048*256
  u16* WtK = WtQ + 2048 * 256;
  u16* WtV = WtK + 2048 * 256;
  u16* Wut = WtV + 2048 * 256;           // 256*2048
  u16* Qm  = Wut + 2048 * 256;           // 8192*2048 each below
  u16* Km  = Qm  + (size_t)8192 * 2048;
  u16* Vm  = Km  + (size_t)8192 * 2048;
  u16* Vtm = Vm  + (size_t)8192 * 2048;
  u16* Om  = Vtm + (size_t)8192 * 2048;

  const float inv4 = 0.25f;  // 256^(-1/4)

  cvt_bf16<<<2048, 256, 0, stream>>>(x, xb, 8192 * 256 / 4);
  transpose_cvt<<<dim3(64, 8), 256, 0, stream>>>(Wq, WtQ, 256, 2048, inv4);
  transpose_cvt<<<dim3(64, 8), 256, 0, stream>>>(Wk, WtK, 256, 2048, inv4);
  transpose_cvt<<<dim3(64, 8), 256, 0, stream>>>(Wv, WtV, 256, 2048, 1.0f);
  transpose_cvt<<<dim3(8, 64), 256, 0, stream>>>(Wu, Wut, 2048, 256, 1.0f);

  gemm_bt<0><<<dim3(16, 64), 256, 0, stream>>>(xb, WtQ, Qm, 8192, 2048, 256, 256, 256, 2048);
  gemm_bt<0><<<dim3(16, 64), 256, 0, stream>>>(xb, WtK, Km, 8192, 2048, 256, 256, 256, 2048);
  gemm_bt<0><<<dim3(16, 64), 256, 0, stream>>>(xb, WtV, Vm, 8192, 2048, 256, 256, 256, 2048);

  transpose_v<<<dim3(8, 32, 64), 256, 0, stream>>>(Vm, Vtm);

  attn_kernel<<<512, 512, 0, stream>>>(Qm, Km, Vtm, Om);

  gemm_bt<1><<<dim3(2, 64), 256, 0, stream>>>(Om, Wut, d_out, 8192, 256, 2048, 2048, 2048, 256);
}